// Round 1
// baseline (460.618 us; speedup 1.0000x reference)
//
#include <hip/hip_runtime.h>
#include <stdint.h>

// QuantConv1d: out[m][n] = (sum_k x[m][k]*w[k][n]) * scale[n] + bias[n]
// m=256 tokens, k=4096, n=16384. w arrives as int32 per harness ("integer -> const int*").
// HBM-bound: 256 MiB weight stream => ~44 us floor. Strategy: bf16 MFMA (int8 weights
// are exact in bf16), stream W once (BM=256 => disjoint column stripes per block),
// in-register int32->bf16 transpose into fragment-major LDS, A-frags direct from
// L2-resident pre-converted bf16 x.

typedef short bf16x8 __attribute__((ext_vector_type(8)));   // 8 bf16 = 16 B (MFMA A/B frag)
typedef float f32x16 __attribute__((ext_vector_type(16)));  // MFMA 32x32 accumulator
typedef int   i32x4  __attribute__((ext_vector_type(4)));
typedef int   i32x2  __attribute__((ext_vector_type(2)));
typedef unsigned short u16x4 __attribute__((ext_vector_type(4)));

#define K_DIM 4096
#define N_DIM 16384
#define BK 128
#define BN 64
#define NIT (K_DIM / BK)   // 32 K-iterations

__device__ __forceinline__ unsigned fbits(float f) {
  union { float f; unsigned u; } c; c.f = f; return c.u;
}

// ---------------- kernel 1: x fp32 -> bf16 (RNE) into workspace ----------------
__global__ __launch_bounds__(256) void cvt_x_bf16(const float* __restrict__ x,
                                                  unsigned short* __restrict__ xb) {
  int id = blockIdx.x * 256 + threadIdx.x;     // 262144 threads * 4 floats = 1048576
  float4 v = ((const float4*)x)[id];
  u16x4 o;
  unsigned u;
  u = fbits(v.x); o.x = (unsigned short)((u + 0x7FFFu + ((u >> 16) & 1u)) >> 16);
  u = fbits(v.y); o.y = (unsigned short)((u + 0x7FFFu + ((u >> 16) & 1u)) >> 16);
  u = fbits(v.z); o.z = (unsigned short)((u + 0x7FFFu + ((u >> 16) & 1u)) >> 16);
  u = fbits(v.w); o.w = (unsigned short)((u + 0x7FFFu + ((u >> 16) & 1u)) >> 16);
  ((u16x4*)xb)[id] = o;
}

// ---------------- kernel 2: GEMM ----------------
// block: 512 thr = 8 waves as 4(m) x 2(n); wave-tile 64x32 = two 32x32 MFMA tiles.
// grid: 256 blocks, block bx owns output columns [bx*64, bx*64+64) for ALL 256 rows.
__global__ __launch_bounds__(512, 2) void gemm_qconv(
    const unsigned short* __restrict__ xb,   // [256][4096] bf16
    const int* __restrict__ w,               // [4096][16384] int32
    const float* __restrict__ scale,
    const float* __restrict__ bias,
    float* __restrict__ out) {
  // B fragment store: frag fb = (c*8 + s), c = n32-tile (0..1), s = kstep (0..7).
  // slot sigma = khalf*32 + (n&31); reader lane reads slot==lane => contiguous b128.
  __shared__ i32x4 Blds[16 * 64];            // 16 KiB

  const int tid  = threadIdx.x;
  const int lane = tid & 63;
  const int wave = tid >> 6;
  const int l31  = lane & 31;
  const int half = lane >> 5;
  const int wm   = wave >> 1;                // 0..3 : m64-tile
  const int wn   = wave & 1;                 // 0..1 : n32-tile
  const int n0   = blockIdx.x * BN;

  // ---- W staging assignment: thread t covers 8 k-rows x 2 n-columns per iter ----
  const int n2 = tid & 31;                   // which pair of n columns (2*n2, 2*n2+1)
  const int k8 = tid >> 5;                   // 0..15 : k-rows [k8*8, k8*8+8)
  const int sW = k8 >> 1;                    // kstep this thread feeds
  const int hW = k8 & 1;                     // k-half within kstep
  const int nnA = n2 * 2, nnB = n2 * 2 + 1;  // block-local n of the two chunks
  const int slotA = ((nnA >> 5) * 8 + sW) * 64 + (hW * 32 + (nnA & 31));
  const int slotB = ((nnB >> 5) * 8 + sW) * 64 + (hW * 32 + (nnB & 31));

  const int* wbase = w + (k8 * 8) * N_DIM + n0 + n2 * 2;

  // prologue: prefetch W regs for iter 0 (16 ints = 8 x dwordx2, rows 256B-coalesced)
  i32x2 L[8];
#pragma unroll
  for (int i = 0; i < 8; ++i) L[i] = *(const i32x2*)(wbase + i * N_DIM);

  f32x16 acc0 = {};
  f32x16 acc1 = {};

  // A-frag base pointers: rows (wm*64 + l31) and +32; k offset half*8 within kstep
  const unsigned short* arow0 = xb + (wm * 64 + l31) * K_DIM + half * 8;
  const unsigned short* arow1 = arow0 + 32 * K_DIM;

#pragma unroll 1
  for (int it = 0; it < NIT; ++it) {
    const int kk = it * BK;

    // convert prefetched int32 W -> bf16 (exact: |w|<=128) ; v_cvt + 1 v_perm/pair
    i32x4 chA, chB;
#pragma unroll
    for (int d = 0; d < 4; ++d) {
      float a0 = (float)L[2 * d].x,     a1 = (float)L[2 * d + 1].x;
      float b0 = (float)L[2 * d].y,     b1 = (float)L[2 * d + 1].y;
      chA[d] = (int)__builtin_amdgcn_perm(fbits(a1), fbits(a0), 0x07060302u); // hi16|lo16
      chB[d] = (int)__builtin_amdgcn_perm(fbits(b1), fbits(b0), 0x07060302u);
    }
    Blds[slotA] = chA;
    Blds[slotB] = chB;
    __syncthreads();   // drains ds_writes; B tile ready

    // prefetch W for next iter AFTER the barrier so the drain doesn't kill it
    if (it + 1 < NIT) {
      const int* wp = wbase + (kk + BK) * N_DIM;
#pragma unroll
      for (int i = 0; i < 8; ++i) L[i] = *(const i32x2*)(wp + i * N_DIM);
    }

    // compute: 8 ksteps of 32x32x16 MFMA; A from global (L1/L2-hot), B from LDS
#pragma unroll
    for (int s = 0; s < 8; ++s) {
      const int ko = kk + s * 16;
      bf16x8 a0 = *(const bf16x8*)(arow0 + ko);
      bf16x8 a1 = *(const bf16x8*)(arow1 + ko);
      bf16x8 b  = *(const bf16x8*)&Blds[(wn * 8 + s) * 64 + lane];
      acc0 = __builtin_amdgcn_mfma_f32_32x32x16_bf16(a0, b, acc0, 0, 0, 0);
      acc1 = __builtin_amdgcn_mfma_f32_32x32x16_bf16(a1, b, acc1, 0, 0, 0);
    }
    __syncthreads();   // protect Blds before next iter's writes
  }

  // epilogue: C/D map col=lane&31, row=(reg&3)+8*(reg>>2)+4*half  [verified m74/m101]
  const int n = n0 + wn * 32 + l31;
  const float sc = scale[n];
  const float bs = bias[n];
#pragma unroll
  for (int r = 0; r < 2; ++r) {
    const f32x16 acc = r ? acc1 : acc0;
#pragma unroll
    for (int g = 0; g < 16; ++g) {
      const int m = wm * 64 + r * 32 + (g & 3) + 8 * (g >> 2) + 4 * half;
      out[m * N_DIM + n] = acc[g] * sc + bs;
    }
  }
}

extern "C" void kernel_launch(void* const* d_in, const int* in_sizes, int n_in,
                              void* d_out, int out_size, void* d_ws, size_t ws_size,
                              hipStream_t stream) {
  const float* x     = (const float*)d_in[0];   // [8,32,4096] fp32
  const int*   wgt   = (const int*)d_in[1];     // [4096,16384] int32 (harness-widened int8)
  const float* scale = (const float*)d_in[2];   // [1,16384]
  const float* bias  = (const float*)d_in[3];   // [16384]
  float* out = (float*)d_out;
  unsigned short* xb = (unsigned short*)d_ws;   // 2 MiB bf16 copy of x

  cvt_x_bf16<<<1024, 256, 0, stream>>>(x, xb);
  gemm_qconv<<<256, 512, 0, stream>>>(xb, wgt, scale, bias, out);
}

// Round 2
// 401.662 us; speedup vs baseline: 1.1468x; 1.1468x over previous
//
#include <hip/hip_runtime.h>
#include <stdint.h>

// QuantConv1d: out[m][n] = (sum_k x[m][k]*w[k][n]) * scale[n] + bias[n]
// m=256, k=4096, n=16384. w arrives as int32 (harness-widened int8): 256 MiB stream.
// R1 fix: xb stored in A-fragment-major layout so A-loads are coalesced 1KiB wave
// reads (R1's 64-line/instr gather made the kernel issue-bound at 200us even with
// W fully L3-resident). A-loads hoisted before W prefetch so their vmcnt waits
// don't drain the in-flight HBM weight loads.

typedef short bf16x8 __attribute__((ext_vector_type(8)));   // 8 bf16 = 16 B (MFMA A/B frag)
typedef float f32x16 __attribute__((ext_vector_type(16)));  // MFMA 32x32 accumulator
typedef int   i32x4  __attribute__((ext_vector_type(4)));
typedef int   i32x2  __attribute__((ext_vector_type(2)));
typedef unsigned short u16x4 __attribute__((ext_vector_type(4)));

#define K_DIM 4096
#define N_DIM 16384
#define BK 128
#define BN 64
#define NIT (K_DIM / BK)   // 32 K-iterations
#define KSTEPS 256         // K_DIM/16 total MFMA k-steps

__device__ __forceinline__ unsigned fbits(float f) {
  union { float f; unsigned u; } c; c.f = f; return c.u;
}
__device__ __forceinline__ unsigned short bf16rne(float f) {
  unsigned u = fbits(f);
  return (unsigned short)((u + 0x7FFFu + ((u >> 16) & 1u)) >> 16);
}

// ---------------- kernel 1: x fp32 -> bf16, A-fragment-major ----------------
// chunk c = (mt*256 + ks)*64 + lane holds A[m = mt*32 + (lane&31)]
//                                        [k = ks*16 + (lane>>5)*8 .. +8]  (16 B)
// => a wave's A-frag read for (mt, ks) is 64 contiguous 16 B chunks = 1 KiB.
__global__ __launch_bounds__(256) void cvt_x_frag(const float* __restrict__ x,
                                                  unsigned short* __restrict__ xb) {
  int c    = blockIdx.x * 256 + threadIdx.x;   // 131072 chunks
  int lane = c & 63;
  int ks   = (c >> 6) & 255;
  int mt   = c >> 14;
  int row  = mt * 32 + (lane & 31);
  int k0   = ks * 16 + (lane >> 5) * 8;
  const float4* p = (const float4*)(x + row * K_DIM + k0);
  float4 v0 = p[0], v1 = p[1];
  u16x4 o0, o1;
  o0.x = bf16rne(v0.x); o0.y = bf16rne(v0.y); o0.z = bf16rne(v0.z); o0.w = bf16rne(v0.w);
  o1.x = bf16rne(v1.x); o1.y = bf16rne(v1.y); o1.z = bf16rne(v1.z); o1.w = bf16rne(v1.w);
  u16x4* dst = (u16x4*)(xb + (size_t)c * 8);
  dst[0] = o0;
  dst[1] = o1;
}

// ---------------- kernel 2: GEMM ----------------
// block: 512 thr = 8 waves as 4(m) x 2(n); wave-tile 64x32 = two 32x32 MFMA tiles.
// grid: 256 blocks; block bx owns output columns [bx*64, bx*64+64) for ALL 256 rows
// => every W element fetched from HBM exactly once.
__global__ __launch_bounds__(512, 2) void gemm_qconv(
    const unsigned short* __restrict__ xb,   // A-fragment-major bf16 (see cvt)
    const int* __restrict__ w,               // [4096][16384] int32
    const float* __restrict__ scale,
    const float* __restrict__ bias,
    float* __restrict__ out) {
  // B fragment store: frag fb = (c*8 + s), c = n32-tile (0..1), s = kstep (0..7).
  // slot sigma = khalf*32 + (n&31); reader lane reads slot==lane => contiguous b128.
  __shared__ i32x4 Blds[16 * 64];            // 16 KiB

  const int tid  = threadIdx.x;
  const int lane = tid & 63;
  const int wave = tid >> 6;
  const int l31  = lane & 31;
  const int half = lane >> 5;
  const int wm   = wave >> 1;                // 0..3 : m64-tile
  const int wn   = wave & 1;                 // 0..1 : n32-tile
  const int n0   = blockIdx.x * BN;

  // ---- W staging assignment: thread t covers 8 k-rows x 2 n-columns per iter ----
  const int n2 = tid & 31;                   // column pair (2*n2, 2*n2+1)
  const int k8 = tid >> 5;                   // 0..15 : k-rows [k8*8, k8*8+8)
  const int sW = k8 >> 1;                    // kstep this thread feeds
  const int hW = k8 & 1;                     // k-half within kstep
  const int nnA = n2 * 2, nnB = n2 * 2 + 1;
  const int slotA = ((nnA >> 5) * 8 + sW) * 64 + (hW * 32 + (nnA & 31));
  const int slotB = ((nnB >> 5) * 8 + sW) * 64 + (hW * 32 + (nnB & 31));

  const int* wbase = w + (k8 * 8) * N_DIM + n0 + n2 * 2;

  // prologue: prefetch W regs for iter 0 (16 ints = 8 x dwordx2, rows 256B-coalesced)
  i32x2 L[8];
#pragma unroll
  for (int i = 0; i < 8; ++i) L[i] = *(const i32x2*)(wbase + i * N_DIM);

  f32x16 acc0 = {};
  f32x16 acc1 = {};

  // A-fragment bases: wave wm owns m-tiles mt = wm*2 (acc0) and wm*2+1 (acc1)
  const bf16x8* afrag0 = (const bf16x8*)(xb + (size_t)((wm * 2 + 0) * KSTEPS) * 64 * 8);
  const bf16x8* afrag1 = (const bf16x8*)(xb + (size_t)((wm * 2 + 1) * KSTEPS) * 64 * 8);

#pragma unroll 1
  for (int it = 0; it < NIT; ++it) {
    // convert prefetched int32 W -> bf16 (exact: |w|<=128); v_cvt + 1 v_perm/pair
    i32x4 chA, chB;
#pragma unroll
    for (int d = 0; d < 4; ++d) {
      float a0 = (float)L[2 * d].x,     a1 = (float)L[2 * d + 1].x;
      float b0 = (float)L[2 * d].y,     b1 = (float)L[2 * d + 1].y;
      chA[d] = (int)__builtin_amdgcn_perm(fbits(a1), fbits(a0), 0x07060302u); // hi16|lo16
      chB[d] = (int)__builtin_amdgcn_perm(fbits(b1), fbits(b0), 0x07060302u);
    }
    Blds[slotA] = chA;
    Blds[slotB] = chB;
    __syncthreads();   // B tile ready

    // A-frags for this iteration: coalesced 1KiB wave reads, L1/L2-hot.
    // Issued BEFORE the W prefetch so A waits don't drain the W HBM queue.
    bf16x8 A0[8], A1[8];
#pragma unroll
    for (int s = 0; s < 8; ++s) {
      A0[s] = afrag0[(it * 8 + s) * 64 + lane];
      A1[s] = afrag1[(it * 8 + s) * 64 + lane];
    }

    // prefetch W for next iter (consumed after next barrier => ~full-iter window)
    if (it + 1 < NIT) {
      const int* wp = wbase + (it + 1) * BK * N_DIM;
#pragma unroll
      for (int i = 0; i < 8; ++i) L[i] = *(const i32x2*)(wp + i * N_DIM);
    }

    // compute: 8 ksteps of 32x32x16 MFMA; A from regs, B from LDS
#pragma unroll
    for (int s = 0; s < 8; ++s) {
      bf16x8 b = *(const bf16x8*)&Blds[(wn * 8 + s) * 64 + lane];
      acc0 = __builtin_amdgcn_mfma_f32_32x32x16_bf16(A0[s], b, acc0, 0, 0, 0);
      acc1 = __builtin_amdgcn_mfma_f32_32x32x16_bf16(A1[s], b, acc1, 0, 0, 0);
    }
    __syncthreads();   // protect Blds before next iter's writes
  }

  // epilogue: C/D map col=lane&31, row=(reg&3)+8*(reg>>2)+4*half
  const int n = n0 + wn * 32 + l31;
  const float sc = scale[n];
  const float bs = bias[n];
#pragma unroll
  for (int r = 0; r < 2; ++r) {
    const f32x16 acc = r ? acc1 : acc0;
#pragma unroll
    for (int g = 0; g < 16; ++g) {
      const int m = wm * 64 + r * 32 + (g & 3) + 8 * (g >> 2) + 4 * half;
      out[m * N_DIM + n] = acc[g] * sc + bs;
    }
  }
}

extern "C" void kernel_launch(void* const* d_in, const int* in_sizes, int n_in,
                              void* d_out, int out_size, void* d_ws, size_t ws_size,
                              hipStream_t stream) {
  const float* x     = (const float*)d_in[0];   // [8,32,4096] fp32
  const int*   wgt   = (const int*)d_in[1];     // [4096,16384] int32
  const float* scale = (const float*)d_in[2];   // [1,16384]
  const float* bias  = (const float*)d_in[3];   // [16384]
  float* out = (float*)d_out;
  unsigned short* xb = (unsigned short*)d_ws;   // 2 MiB fragment-major bf16 x

  cvt_x_frag<<<512, 256, 0, stream>>>(x, xb);
  gemm_qconv<<<256, 512, 0, stream>>>(xb, wgt, scale, bias, out);
}